// Round 20
// baseline (55.957 us; speedup 1.0000x reference)
//
#include <hip/hip_runtime.h>
#include <hip/hip_bf16.h>

typedef short bf16x8 __attribute__((ext_vector_type(8)));
typedef float f32x4  __attribute__((ext_vector_type(4)));
typedef float f32x16 __attribute__((ext_vector_type(16)));
typedef unsigned short u16;

#define TOTAL_UNITS 81920                   // u = bv*256 + f*8 + t
#define XPU 144                             // rel floats per unit
#define NBLOCKS 1024                        // 4 blocks/CU demand
#define UPB 80
#define NBATCH 5                            // 16-unit batches
#define ZLD 136                             // zs row pad (u16)

// d_ws tables (bf16 bits):
//   diagB32[128 d][16 r] @ 0     : W_rel diagonal, r>=12 zeroed (P1 B, K=16)
//   Wb     [64 n][128 d] @ 2048  : out_w transposed (P2 B, K=128)
__global__ void setup_tabs(const float* __restrict__ W_rel,
                           const float* __restrict__ out_w,
                           u16* __restrict__ ws) {
    const int i = blockIdx.x * 256 + threadIdx.x;
    if (i < 128 * 16) {
        const int d = i >> 4, r = i & 15;
        const float v = (r < 12) ? W_rel[(r * 128 + d) * 128 + d] : 0.f;
        union { __hip_bfloat16 h; u16 u; } cv; cv.h = __float2bfloat16(v);
        ws[i] = cv.u;
    } else if (i < 128 * 16 + 64 * 128) {
        const int j = i - 128 * 16;
        const int n = j >> 7, d = j & 127;
        union { __hip_bfloat16 h; u16 u; } cv;
        cv.h = __float2bfloat16(out_w[d * 64 + n]);
        ws[i] = cv.u;
    }
}

// NOTE: plain launch_bounds only — min-waves arg caused spill disasters (R2, R13).
__global__ __launch_bounds__(256)
void gal_kernel(const float* __restrict__ src,     // [B,V,MT,MF,128]
                const float* __restrict__ rel,     // [u][144]
                const u16*   __restrict__ diagB,   // [128][16] bf16
                const u16*   __restrict__ Wb,      // [64][128] bf16
                const float* __restrict__ attn_w,  // [64+128]
                const float* __restrict__ out_b,   // [64]
                float* __restrict__ out)           // [B,V,64]
{
    // p-summed z tile: 16 units x 128 d bf16, padded row, double-buffered
    __shared__ __align__(16) u16 zs[2][16][ZLD];   // 8.7 KB

    const int tid  = threadIdx.x;
    const int lane = tid & 63;
    const int wv   = tid >> 6;
    const int col0 = lane & 31;   // 32x32 MFMA col within d-tile
    const int h    = lane >> 5;   // lane half (k-group / C row-half)
    const int c    = lane & 15;   // P2 16x16 col
    const int g    = lane >> 4;   // P2 k-group

    const int u_base = blockIdx.x * UPB;
    const int bv0    = u_base >> 8;

    // P1 B-frags (diag, K=16): d = t*32+col0, r = h*8 + j (r>=12 zero)
    bf16x8 dgf[4];
#pragma unroll
    for (int t = 0; t < 4; ++t)
        dgf[t] = *(const bf16x8*)(diagB + (t * 32 + col0) * 16 + h * 8);
    // P2 B-frags (out_w, K=128)
    bf16x8 wbf[4];
#pragma unroll
    for (int ks = 0; ks < 4; ++ks)
        wbf[ks] = *(const bf16x8*)(Wb + (wv * 16 + c) * 128 + ks * 32 + g * 8);

    const float LOG2E = 1.4426950408889634f;
    float aw4[4];
#pragma unroll
    for (int t = 0; t < 4; ++t)
        aw4[t] = attn_w[64 + t * 32 + col0] * LOG2E;
    const float ob = out_b[wv * 16 + c];

    // A-row geometry: row = lane&31 -> unit uloc = row>>4, slot w4 = row&15.
    // p = perm[w4>>2], perm = {0,2,1,3}; k = w4&3 (k==3 pad dups k=2, unused C row)
    const int uloc = (lane & 31) >> 4;
    const int w4   = lane & 15;
    const int sel  = w4 >> 2;
    const int p    = (sel == 1) ? 2 : ((sel == 2) ? 1 : sel);
    const int kk   = (w4 & 3) < 3 ? (w4 & 3) : 2;
    const int aoffA = uloc * XPU + p * 36 + kk * 12 + h * 8;  // r = 8h..8h+3
    const int aoffB = uloc * XPU + p * 36 + kk * 12 + 4;      // r = 4..7 (h=0)

    const f32x4  zero4  = {0.f, 0.f, 0.f, 0.f};
    const f32x16 zero16 = {0.f,0.f,0.f,0.f,0.f,0.f,0.f,0.f,
                           0.f,0.f,0.f,0.f,0.f,0.f,0.f,0.f};
    float accA = 0.f, accB = 0.f;

    for (int b = 0; b < NBATCH; ++b) {
        const int X   = b & 1;
        const int ub0 = u_base + b * 16;

        // ---- P1: 2 passes, each wave computes 2 units per pass ----
#pragma unroll 1
        for (int ps = 0; ps < 2; ++ps) {
            const int base_u = ub0 + ps * 8 + wv * 2;
            const float* __restrict__ relb = rel + base_u * XPU;
            const float4 La = *(const float4*)(relb + aoffA);
            const float4 Lb = *(const float4*)(relb + aoffB);

            const int u0 = base_u, u1 = base_u + 1;
            const int ubv = u0 >> 8;   // unit's OWN bv (R16 bugfix)
            const int so0 = ((ubv * 8 + (u0 & 7)) * 32 + ((u0 >> 3) & 31)) * 128;
            const int so1 = ((ubv * 8 + (u1 & 7)) * 32 + ((u1 >> 3) & 31)) * 128;
            float s0[4], s1[4];
#pragma unroll
            for (int t = 0; t < 4; ++t) {
                s0[t] = src[so0 + t * 32 + col0];
                s1[t] = src[so1 + t * 32 + col0];
            }

            // A-frag: 8 bf16 = r-slice 8h..8h+7 of this row's rel values
            union { __hip_bfloat162 hh; unsigned int q; } q0, q1, q2, q3;
            q0.hh = __float22bfloat162_rn(make_float2(La.x, La.y));
            q1.hh = __float22bfloat162_rn(make_float2(La.z, La.w));
            q2.hh = __float22bfloat162_rn(make_float2(Lb.x, Lb.y));
            q3.hh = __float22bfloat162_rn(make_float2(Lb.z, Lb.w));
            union { bf16x8 v; unsigned int q[4]; } af;
            af.q[0] = q0.q;              // h=0: r0-1 ; h=1: r8-9
            af.q[1] = q1.q;              // h=0: r2-3 ; h=1: r10-11
            af.q[2] = h ? 0u : q2.q;     // h=1 tail r12-15 = 0 (B also zero)
            af.q[3] = h ? 0u : q3.q;

            // 4 MFMAs in two pairs. A FALSE DATA DEPENDENCY (empty asm that
            // "writes" the second pair's B-operands and reads the first pair's
            // consumed products) serializes pair 2 after pair 1's consumption:
            // only 2 f32x16 accumulators are ever co-live (32 regs, not 64),
            // keeping unified VGPR+AGPR under the 128/wave, 4-waves/SIMD line.
            // Unlike sched_barrier(0) (R19), liveness elsewhere is untouched.
            float w[4][4];
            {
                const f32x16 pa0 = __builtin_amdgcn_mfma_f32_32x32x16_bf16(
                    af.v, dgf[0], zero16, 0, 0, 0);
                const f32x16 pa1 = __builtin_amdgcn_mfma_f32_32x32x16_bf16(
                    af.v, dgf[1], zero16, 0, 0, 0);
                w[0][0] = pa0[0]  * pa0[1]  * pa0[2];
                w[1][0] = pa0[4]  * pa0[5]  * pa0[6];
                w[2][0] = pa0[8]  * pa0[9]  * pa0[10];
                w[3][0] = pa0[12] * pa0[13] * pa0[14];
                w[0][1] = pa1[0]  * pa1[1]  * pa1[2];
                w[1][1] = pa1[4]  * pa1[5]  * pa1[6];
                w[2][1] = pa1[8]  * pa1[9]  * pa1[10];
                w[3][1] = pa1[12] * pa1[13] * pa1[14];
            }
            asm volatile("" : "+v"(dgf[2]), "+v"(dgf[3])
                         : "v"(w[0][0]), "v"(w[1][0]), "v"(w[2][0]), "v"(w[3][0]),
                           "v"(w[0][1]), "v"(w[1][1]), "v"(w[2][1]), "v"(w[3][1]));
            {
                const f32x16 pa2 = __builtin_amdgcn_mfma_f32_32x32x16_bf16(
                    af.v, dgf[2], zero16, 0, 0, 0);
                const f32x16 pa3 = __builtin_amdgcn_mfma_f32_32x32x16_bf16(
                    af.v, dgf[3], zero16, 0, 0, 0);
                w[0][2] = pa2[0]  * pa2[1]  * pa2[2];
                w[1][2] = pa2[4]  * pa2[5]  * pa2[6];
                w[2][2] = pa2[8]  * pa2[9]  * pa2[10];
                w[3][2] = pa2[12] * pa2[13] * pa2[14];
                w[0][3] = pa3[0]  * pa3[1]  * pa3[2];
                w[1][3] = pa3[4]  * pa3[5]  * pa3[6];
                w[2][3] = pa3[8]  * pa3[9]  * pa3[10];
                w[3][3] = pa3[12] * pa3[13] * pa3[14];
            }

            // logit partials, then one shared 5-step butterfly over 32 cols
            float lp0 = 0.f, lp1 = 0.f, lp2 = 0.f, lp3 = 0.f;
#pragma unroll
            for (int t = 0; t < 4; ++t) {
                const float sa0 = s0[t] * aw4[t];
                const float sa1 = s1[t] * aw4[t];
                lp0 = fmaf(w[0][t], sa0, lp0);
                lp1 = fmaf(w[1][t], sa0, lp1);
                lp2 = fmaf(w[2][t], sa1, lp2);
                lp3 = fmaf(w[3][t], sa1, lp3);
            }
#pragma unroll
            for (int off = 1; off <= 16; off <<= 1) {
                lp0 += __shfl_xor(lp0, off);
                lp1 += __shfl_xor(lp1, off);
                lp2 += __shfl_xor(lp2, off);
                lp3 += __shfl_xor(lp3, off);
            }
            const float o0 = __shfl_xor(lp0, 32);   // other half's paths
            const float o1 = __shfl_xor(lp1, 32);
            const float o2 = __shfl_xor(lp2, 32);
            const float o3 = __shfl_xor(lp3, 32);

            // softmax per unit over 4 paths (log2 domain; uniform terms cancel)
            const float m0 = fmaxf(fmaxf(lp0, lp1), fmaxf(o0, o1));
            const float eA0 = exp2f(lp0 - m0), eB0 = exp2f(lp1 - m0);
            const float S0  = eA0 + eB0 + exp2f(o0 - m0) + exp2f(o1 - m0);
            const float i0  = __builtin_amdgcn_rcpf(S0);
            const float a00 = eA0 * i0, a01 = eB0 * i0;

            const float m1 = fmaxf(fmaxf(lp2, lp3), fmaxf(o2, o3));
            const float eA1 = exp2f(lp2 - m1), eB1 = exp2f(lp3 - m1);
            const float S1  = eA1 + eB1 + exp2f(o2 - m1) + exp2f(o3 - m1);
            const float i1  = __builtin_amdgcn_rcpf(S1);
            const float a10 = eA1 * i1, a11 = eB1 * i1;

            // p-sum in registers (own half's 2 paths + exchanged half)
            float zA[4], zB[4];
#pragma unroll
            for (int t = 0; t < 4; ++t) {
                zA[t] = a00 * w[0][t] + a01 * w[1][t];
                zB[t] = a10 * w[2][t] + a11 * w[3][t];
            }
#pragma unroll
            for (int t = 0; t < 4; ++t) {
                zA[t] += __shfl_xor(zA[t], 32);
                zB[t] += __shfl_xor(zB[t], 32);
            }

            // store: half h stores tiles {2h, 2h+1} for both units
            const int slotA = ps * 8 + wv * 2;
#pragma unroll
            for (int tt = 0; tt < 2; ++tt) {
                const float za = h ? zA[2 + tt] : zA[tt];  // static idx select
                const float zb = h ? zB[2 + tt] : zB[tt];
                const float sa = h ? s0[2 + tt] : s0[tt];
                const float sb = h ? s1[2 + tt] : s1[tt];
                const int   dc = (2 * h + tt) * 32 + col0;
                union { __hip_bfloat16 hh; u16 u; } c0, c1;
                c0.hh = __float2bfloat16(za * sa);
                c1.hh = __float2bfloat16(zb * sb);
                zs[X][slotA][dc]     = c0.u;
                zs[X][slotA + 1][dc] = c1.u;
            }
        }

        __syncthreads();   // zs[X] complete; zs[X^1] untouched this batch

        // ---- P2: [16 units x K=128] @ Wb -> C[units, n]; wave = N-tile wv ----
        f32x4 ca = zero4;
#pragma unroll
        for (int ks = 0; ks < 4; ++ks) {
            const bf16x8 az = *(const bf16x8*)(&zs[X][c][ks * 32 + g * 8]);
            ca = __builtin_amdgcn_mfma_f32_16x16x32_bf16(az, wbf[ks], ca, 0, 0, 0);
        }
        float su = 0.f;
#pragma unroll
        for (int i = 0; i < 4; ++i)
            su += fmaxf(ca[i] + ob, 0.f);     // unit rows g*4+i
        if ((ub0 >> 8) == bv0) accA += su; else accB += su;
        // 16-unit batches never straddle a bv boundary (256 % 16 == 0)
    }

    // reduce over row-groups (g) and emit: wave owns distinct n-range
    accA += __shfl_xor(accA, 16); accA += __shfl_xor(accA, 32);
    accB += __shfl_xor(accB, 16); accB += __shfl_xor(accB, 32);
    if (lane < 16) {
        atomicAdd(&out[bv0 * 64 + wv * 16 + lane], accA);
        const int bvL = (u_base + UPB - 1) >> 8;
        if (bvL != bv0) atomicAdd(&out[bvL * 64 + wv * 16 + lane], accB);
    }
}

extern "C" void kernel_launch(void* const* d_in, const int* in_sizes, int n_in,
                              void* d_out, int out_size, void* d_ws, size_t ws_size,
                              hipStream_t stream) {
    const float* src    = (const float*)d_in[0];  // source_embed
    const float* rel    = (const float*)d_in[1];  // rel_index
    // d_in[2] = s        (cancels in softmax)
    const float* W_rel  = (const float*)d_in[3];
    const float* attn_w = (const float*)d_in[4];
    // d_in[5] = attn_b   (cancels in softmax)
    const float* out_w  = (const float*)d_in[6];
    const float* out_b  = (const float*)d_in[7];
    float* out  = (float*)d_out;
    u16*   tabs = (u16*)d_ws;                     // 20.5 KB of bf16 tables

    hipMemsetAsync(out, 0, (size_t)out_size * sizeof(float), stream);
    setup_tabs<<<40, 256, 0, stream>>>(W_rel, out_w, tabs);
    gal_kernel<<<NBLOCKS, 256, 0, stream>>>(src, rel, tabs, tabs + 128 * 16,
                                            attn_w, out_b, out);
}

// Round 21
// 42.390 us; speedup vs baseline: 1.3200x; 1.3200x over previous
//
#include <hip/hip_runtime.h>
#include <hip/hip_bf16.h>

typedef short bf16x8 __attribute__((ext_vector_type(8)));
typedef float f32x4  __attribute__((ext_vector_type(4)));
typedef float f32x16 __attribute__((ext_vector_type(16)));
typedef unsigned short u16;

#define TOTAL_UNITS 81920                   // u = bv*256 + f*8 + t
#define XPU 144                             // rel floats per unit
#define NBLOCKS 1024                        // 4 blocks/CU
#define UPB 80
#define NBATCH 5                            // 16-unit batches
#define ZLD 136                             // zs row pad (u16): banks spread 4/row

// d_ws tables (bf16 bits):
//   diagB32[128 d][16 r] @ 0     : W_rel diagonal, r>=12 zeroed (P1 B, K=16)
//   Wb     [64 n][128 d] @ 2048  : out_w transposed (P2 B, K=128)
__global__ void setup_tabs(const float* __restrict__ W_rel,
                           const float* __restrict__ out_w,
                           u16* __restrict__ ws) {
    const int i = blockIdx.x * 256 + threadIdx.x;
    if (i < 128 * 16) {
        const int d = i >> 4, r = i & 15;
        const float v = (r < 12) ? W_rel[(r * 128 + d) * 128 + d] : 0.f;
        union { __hip_bfloat16 h; u16 u; } cv; cv.h = __float2bfloat16(v);
        ws[i] = cv.u;
    } else if (i < 128 * 16 + 64 * 128) {
        const int j = i - 128 * 16;
        const int n = j >> 7, d = j & 127;
        union { __hip_bfloat16 h; u16 u; } cv;
        cv.h = __float2bfloat16(out_w[d * 64 + n]);
        ws[i] = cv.u;
    }
}

// NOTE: plain launch_bounds only — min-waves arg caused spill disasters (R2, R13).
// R18-R20 established: do NOT touch the MFMA schedule (grid-widening, sched_barrier,
// false-dep all regressed via higher unified VGPR+AGPR liveness). This is the
// session's measured optimum structure.
__global__ __launch_bounds__(256)
void gal_kernel(const float* __restrict__ src,     // [B,V,MT,MF,128]
                const float* __restrict__ rel,     // [u][144]
                const u16*   __restrict__ diagB,   // [128][16] bf16
                const u16*   __restrict__ Wb,      // [64][128] bf16
                const float* __restrict__ attn_w,  // [64+128]
                const float* __restrict__ out_b,   // [64]
                float* __restrict__ out)           // [B,V,64]
{
    // p-summed z tile: 16 units x 128 d bf16, padded row, double-buffered
    __shared__ __align__(16) u16 zs[2][16][ZLD];   // 8.7 KB

    const int tid  = threadIdx.x;
    const int lane = tid & 63;
    const int wv   = tid >> 6;
    const int col0 = lane & 31;   // 32x32 MFMA col within d-tile
    const int h    = lane >> 5;   // lane half (k-group / C row-half)
    const int c    = lane & 15;   // P2 16x16 col
    const int g    = lane >> 4;   // P2 k-group

    const int u_base = blockIdx.x * UPB;
    const int bv0    = u_base >> 8;

    // P1 B-frags (diag, K=16): d = t*32+col0, r = h*8 + j (r>=12 zero)
    bf16x8 dgf[4];
#pragma unroll
    for (int t = 0; t < 4; ++t)
        dgf[t] = *(const bf16x8*)(diagB + (t * 32 + col0) * 16 + h * 8);
    // P2 B-frags (out_w, K=128)
    bf16x8 wbf[4];
#pragma unroll
    for (int ks = 0; ks < 4; ++ks)
        wbf[ks] = *(const bf16x8*)(Wb + (wv * 16 + c) * 128 + ks * 32 + g * 8);

    const float LOG2E = 1.4426950408889634f;
    float aw4[4];
#pragma unroll
    for (int t = 0; t < 4; ++t)
        aw4[t] = attn_w[64 + t * 32 + col0] * LOG2E;
    const float ob = out_b[wv * 16 + c];

    // A-row geometry: row = lane&31 -> unit uloc = row>>4, slot w4 = row&15.
    // p = perm[w4>>2], perm = {0,2,1,3}; k = w4&3 (k==3 pad dups k=2, unused C row)
    const int uloc = (lane & 31) >> 4;
    const int w4   = lane & 15;
    const int sel  = w4 >> 2;
    const int p    = (sel == 1) ? 2 : ((sel == 2) ? 1 : sel);
    const int kk   = (w4 & 3) < 3 ? (w4 & 3) : 2;
    const int aoffA = uloc * XPU + p * 36 + kk * 12 + h * 8;  // r = 8h..8h+3
    const int aoffB = uloc * XPU + p * 36 + kk * 12 + 4;      // r = 4..7 (h=0)

    const f32x4  zero4  = {0.f, 0.f, 0.f, 0.f};
    const f32x16 zero16 = {0.f,0.f,0.f,0.f,0.f,0.f,0.f,0.f,
                           0.f,0.f,0.f,0.f,0.f,0.f,0.f,0.f};
    float accA = 0.f, accB = 0.f;

    for (int b = 0; b < NBATCH; ++b) {
        const int X   = b & 1;
        const int ub0 = u_base + b * 16;

        // ---- P1: 2 passes, each wave computes 2 units per pass ----
#pragma unroll 1
        for (int ps = 0; ps < 2; ++ps) {
            const int base_u = ub0 + ps * 8 + wv * 2;
            const float* __restrict__ relb = rel + base_u * XPU;
            const float4 La = *(const float4*)(relb + aoffA);
            const float4 Lb = *(const float4*)(relb + aoffB);

            const int u0 = base_u, u1 = base_u + 1;
            const int ubv = u0 >> 8;   // unit's OWN bv (R16 bugfix)
            const int so0 = ((ubv * 8 + (u0 & 7)) * 32 + ((u0 >> 3) & 31)) * 128;
            const int so1 = ((ubv * 8 + (u1 & 7)) * 32 + ((u1 >> 3) & 31)) * 128;
            float s0[4], s1[4];
#pragma unroll
            for (int t = 0; t < 4; ++t) {
                s0[t] = src[so0 + t * 32 + col0];
                s1[t] = src[so1 + t * 32 + col0];
            }

            // A-frag: 8 bf16 = r-slice 8h..8h+7 of this row's rel values
            union { __hip_bfloat162 hh; unsigned int q; } q0, q1, q2, q3;
            q0.hh = __float22bfloat162_rn(make_float2(La.x, La.y));
            q1.hh = __float22bfloat162_rn(make_float2(La.z, La.w));
            q2.hh = __float22bfloat162_rn(make_float2(Lb.x, Lb.y));
            q3.hh = __float22bfloat162_rn(make_float2(Lb.z, Lb.w));
            union { bf16x8 v; unsigned int q[4]; } af;
            af.q[0] = q0.q;              // h=0: r0-1 ; h=1: r8-9
            af.q[1] = q1.q;              // h=0: r2-3 ; h=1: r10-11
            af.q[2] = h ? 0u : q2.q;     // h=1 tail r12-15 = 0 (B also zero)
            af.q[3] = h ? 0u : q3.q;

            // 4 MFMAs (one per 32-wide d-tile); k-products per C row-group:
            // gi: 0=(u0,pLo) 1=(u0,pHi) 2=(u1,pLo) 3=(u1,pHi), pLo/pHi by half
            float w[4][4];
#pragma unroll
            for (int t = 0; t < 4; ++t) {
                const f32x16 pa = __builtin_amdgcn_mfma_f32_32x32x16_bf16(
                    af.v, dgf[t], zero16, 0, 0, 0);
                w[0][t] = pa[0]  * pa[1]  * pa[2];
                w[1][t] = pa[4]  * pa[5]  * pa[6];
                w[2][t] = pa[8]  * pa[9]  * pa[10];
                w[3][t] = pa[12] * pa[13] * pa[14];
            }

            // logit partials, then one shared 5-step butterfly over 32 cols
            float lp0 = 0.f, lp1 = 0.f, lp2 = 0.f, lp3 = 0.f;
#pragma unroll
            for (int t = 0; t < 4; ++t) {
                const float sa0 = s0[t] * aw4[t];
                const float sa1 = s1[t] * aw4[t];
                lp0 = fmaf(w[0][t], sa0, lp0);
                lp1 = fmaf(w[1][t], sa0, lp1);
                lp2 = fmaf(w[2][t], sa1, lp2);
                lp3 = fmaf(w[3][t], sa1, lp3);
            }
#pragma unroll
            for (int off = 1; off <= 16; off <<= 1) {
                lp0 += __shfl_xor(lp0, off);
                lp1 += __shfl_xor(lp1, off);
                lp2 += __shfl_xor(lp2, off);
                lp3 += __shfl_xor(lp3, off);
            }
            const float o0 = __shfl_xor(lp0, 32);   // other half's paths
            const float o1 = __shfl_xor(lp1, 32);
            const float o2 = __shfl_xor(lp2, 32);
            const float o3 = __shfl_xor(lp3, 32);

            // softmax per unit over 4 paths (log2 domain; uniform terms cancel)
            const float m0 = fmaxf(fmaxf(lp0, lp1), fmaxf(o0, o1));
            const float eA0 = exp2f(lp0 - m0), eB0 = exp2f(lp1 - m0);
            const float S0  = eA0 + eB0 + exp2f(o0 - m0) + exp2f(o1 - m0);
            const float i0  = __builtin_amdgcn_rcpf(S0);
            const float a00 = eA0 * i0, a01 = eB0 * i0;

            const float m1 = fmaxf(fmaxf(lp2, lp3), fmaxf(o2, o3));
            const float eA1 = exp2f(lp2 - m1), eB1 = exp2f(lp3 - m1);
            const float S1  = eA1 + eB1 + exp2f(o2 - m1) + exp2f(o3 - m1);
            const float i1  = __builtin_amdgcn_rcpf(S1);
            const float a10 = eA1 * i1, a11 = eB1 * i1;

            // p-sum in registers (own half's 2 paths + exchanged half)
            float zA[4], zB[4];
#pragma unroll
            for (int t = 0; t < 4; ++t) {
                zA[t] = a00 * w[0][t] + a01 * w[1][t];
                zB[t] = a10 * w[2][t] + a11 * w[3][t];
            }
#pragma unroll
            for (int t = 0; t < 4; ++t) {
                zA[t] += __shfl_xor(zA[t], 32);
                zB[t] += __shfl_xor(zB[t], 32);
            }

            // store: half h stores tiles {2h, 2h+1} for both units
            const int slotA = ps * 8 + wv * 2;
#pragma unroll
            for (int tt = 0; tt < 2; ++tt) {
                const float za = h ? zA[2 + tt] : zA[tt];  // static idx select
                const float zb = h ? zB[2 + tt] : zB[tt];
                const float sa = h ? s0[2 + tt] : s0[tt];
                const float sb = h ? s1[2 + tt] : s1[tt];
                const int   dc = (2 * h + tt) * 32 + col0;
                union { __hip_bfloat16 hh; u16 u; } c0, c1;
                c0.hh = __float2bfloat16(za * sa);
                c1.hh = __float2bfloat16(zb * sb);
                zs[X][slotA][dc]     = c0.u;
                zs[X][slotA + 1][dc] = c1.u;
            }
        }

        __syncthreads();   // zs[X] complete; zs[X^1] untouched this batch

        // ---- P2: [16 units x K=128] @ Wb -> C[units, n]; wave = N-tile wv ----
        f32x4 ca = zero4;
#pragma unroll
        for (int ks = 0; ks < 4; ++ks) {
            const bf16x8 az = *(const bf16x8*)(&zs[X][c][ks * 32 + g * 8]);
            ca = __builtin_amdgcn_mfma_f32_16x16x32_bf16(az, wbf[ks], ca, 0, 0, 0);
        }
        float su = 0.f;
#pragma unroll
        for (int i = 0; i < 4; ++i)
            su += fmaxf(ca[i] + ob, 0.f);     // unit rows g*4+i
        if ((ub0 >> 8) == bv0) accA += su; else accB += su;
        // 16-unit batches never straddle a bv boundary (256 % 16 == 0)
    }

    // reduce over row-groups (g) and emit: wave owns distinct n-range
    accA += __shfl_xor(accA, 16); accA += __shfl_xor(accA, 32);
    accB += __shfl_xor(accB, 16); accB += __shfl_xor(accB, 32);
    if (lane < 16) {
        atomicAdd(&out[bv0 * 64 + wv * 16 + lane], accA);
        const int bvL = (u_base + UPB - 1) >> 8;
        if (bvL != bv0) atomicAdd(&out[bvL * 64 + wv * 16 + lane], accB);
    }
}

extern "C" void kernel_launch(void* const* d_in, const int* in_sizes, int n_in,
                              void* d_out, int out_size, void* d_ws, size_t ws_size,
                              hipStream_t stream) {
    const float* src    = (const float*)d_in[0];  // source_embed
    const float* rel    = (const float*)d_in[1];  // rel_index
    // d_in[2] = s        (cancels in softmax)
    const float* W_rel  = (const float*)d_in[3];
    const float* attn_w = (const float*)d_in[4];
    // d_in[5] = attn_b   (cancels in softmax)
    const float* out_w  = (const float*)d_in[6];
    const float* out_b  = (const float*)d_in[7];
    float* out  = (float*)d_out;
    u16*   tabs = (u16*)d_ws;                     // 20.5 KB of bf16 tables

    hipMemsetAsync(out, 0, (size_t)out_size * sizeof(float), stream);
    setup_tabs<<<40, 256, 0, stream>>>(W_rel, out_w, tabs);
    gal_kernel<<<NBLOCKS, 256, 0, stream>>>(src, rel, tabs, tabs + 128 * 16,
                                            attn_w, out_b, out);
}